// Round 4
// baseline (2156.872 us; speedup 1.0000x reference)
//
#include <hip/hip_runtime.h>
#include <hip/hip_cooperative_groups.h>

namespace cg = cooperative_groups;

#define N_NODES 10000
#define F_IN    256
#define H1      128
#define H2      64
#define NEDGE   320000
#define M_TOT   (NEDGE + N_NODES)

#define NT 256

typedef __attribute__((ext_vector_type(8))) short          s16v8;  // 8 bf16 (4 VGPRs)
typedef __attribute__((ext_vector_type(8))) unsigned short u16v8;
typedef __attribute__((ext_vector_type(4))) float          f32v4;

// ---------------------------------------------------------------- mega prep
// {init, count||gemm1, scan, scatter, agg1, gemm23, agg2} in ONE cooperative
// kernel. Round-3 failure was grid sizing (512 blocks = 24% occupancy ->
// latency-bound phases cratered at 122 GB/s). v2: occupancy-query-sized grid
// (8 blocks/CU target via launch_bounds(256,8) => VGPR<=64), gemm1 overlapped
// with count, one fewer grid.sync in the scan.
__global__ __launch_bounds__(NT, 8) void k_mega(
    const float* __restrict__ x,  const int* __restrict__ ei, const float* __restrict__ w,
    const float* __restrict__ W1, const float* __restrict__ b1,
    const float* __restrict__ W2, const float* __restrict__ b2,
    const float* __restrict__ W3, const float* __restrict__ b3,
    float* deg, int* cnt, int* ptr, int* cur, int* part,
    int* src, float* wgt, float* hw, float* h1, float* t2, float* t3,
    float* mu, float* lv)
{
    cg::grid_group grid = cg::this_grid();
    __shared__ float smem[16 * F_IN];          // 16 KB staging, reused per phase
    __shared__ int   wsum[8];
    __shared__ int   boff;
    int tid  = threadIdx.x;
    int bid  = blockIdx.x;
    int nbg  = gridDim.x;
    int gtid = bid * NT + tid;
    int gstr = nbg * NT;

    // ---- phase A: init deg/cnt (self-loop weight 1, count 1) ----
    for (int i = gtid; i < N_NODES; i += gstr) { deg[i] = 1.0f; cnt[i] = 1; }
    __threadfence();
    grid.sync();

    // ---- phase B: gemm1 (hw = x@W1) || degree count (disjoint outputs) ----
    for (int tile = bid; tile < N_NODES / 16; tile += nbg) {
        int i0 = tile * 16;
        __syncthreads();
        const float4* xsrc = (const float4*)(x + (size_t)i0 * F_IN);
        float4* xd = (float4*)smem;
#pragma unroll
        for (int j = 0; j < 4; j++) xd[tid + j * 256] = xsrc[tid + j * 256];
        __syncthreads();
        int col = tid & 127, half = tid >> 7;
        const float* xrow = smem + (half * 8) * F_IN;
        float acc[8] = {0, 0, 0, 0, 0, 0, 0, 0};
        for (int k = 0; k < F_IN; k += 4) {
            float w0 = W1[(k + 0) * H1 + col];
            float w1 = W1[(k + 1) * H1 + col];
            float w2 = W1[(k + 2) * H1 + col];
            float w3 = W1[(k + 3) * H1 + col];
#pragma unroll
            for (int r = 0; r < 8; r++) {
                float4 xv = *(const float4*)&xrow[r * F_IN + k];   // wave-uniform bcast
                acc[r] += xv.x * w0 + xv.y * w1 + xv.z * w2 + xv.w * w3;
            }
        }
#pragma unroll
        for (int r = 0; r < 8; r++)
            hw[(size_t)(i0 + half * 8 + r) * H1 + col] = acc[r];
    }
    if (nbg >= 1024) {
        // blocks >= 625 have no gemm tile: they do the count concurrently
        if (bid >= 625) {
            for (int e = (bid - 625) * NT + tid; e < NEDGE; e += (nbg - 625) * NT) {
                int c = ei[NEDGE + e];
                atomicAdd(&deg[c], w[e]);
                atomicAdd(&cnt[c], 1);
            }
        }
    } else {
        for (int e = gtid; e < NEDGE; e += gstr) {
            int c = ei[NEDGE + e];
            atomicAdd(&deg[c], w[e]);
            atomicAdd(&cnt[c], 1);
        }
    }
    __threadfence();
    grid.sync();

    // ---- phase C: scan step 1 — blocks 0..39, block-local exclusive scan ----
    int myExcl = 0;                            // survives across grid syncs in regs
    if (bid < 40) {
        int v = (gtid < N_NODES) ? cnt[gtid] : 0;
        int lane = tid & 63, wv = tid >> 6;
        int xi = v;                            // wave inclusive scan
#pragma unroll
        for (int d = 1; d < 64; d <<= 1) {
            int y = __shfl_up(xi, d, 64);
            if (lane >= d) xi += y;
        }
        if (lane == 63) wsum[wv] = xi;
        __syncthreads();
        if (tid == 0) {
            int s = 0;
#pragma unroll
            for (int i2 = 0; i2 < 4; i2++) { int tt = wsum[i2]; wsum[i2] = s; s += tt; }
            wsum[7] = s;
        }
        __syncthreads();
        myExcl = xi - v + wsum[wv];
        if (tid == 0) part[bid] = wsum[7];
    }
    __threadfence();
    grid.sync();

    // ---- phase E: scan finish — each scan block re-scans the 40 partials ----
    if (bid < 40) {
        if (tid < 64) {
            int v = (tid < 40) ? part[tid] : 0;
            int xi = v;
#pragma unroll
            for (int d = 1; d < 64; d <<= 1) {
                int y = __shfl_up(xi, d, 64);
                if (tid >= d) xi += y;
            }
            int e = __shfl(xi - v, bid, 64);   // exclusive prefix at index bid
            if (tid == 0) boff = e;
        }
        __syncthreads();
        if (gtid < N_NODES) {
            int p = boff + myExcl;
            ptr[gtid] = p; cur[gtid] = p;
        }
        if (gtid == 0) ptr[N_NODES] = M_TOT;   // total is data-independent
    }
    __threadfence();
    grid.sync();

    // ---- phase F: scatter into CSR-by-col (rsqrt folded in) ----
    for (int t = gtid; t < M_TOT; t += gstr) {
        int r, c; float nw;
        if (t < NEDGE) {
            r = ei[t]; c = ei[NEDGE + t];
            nw = rsqrtf(deg[r]) * w[t] * rsqrtf(deg[c]);
        } else {
            r = c = t - NEDGE;
            float d = rsqrtf(deg[r]);
            nw = d * d;
        }
        int pos = atomicAdd(&cur[c], 1);
        src[pos] = r; wgt[pos] = nw;
    }
    __threadfence();
    grid.sync();

    // ---- phase G: agg1  h1 = relu(segsum + b1), 2 nodes per chunk ----
    for (int ch = bid; ch < N_NODES / 2; ch += nbg) {
        int i = ch * 2 + (tid >> 7);           // per-half-block node
        int f = tid & 127;
        int jb = ptr[i], je = ptr[i + 1];
        float acc = b1[f];
        for (int j = jb; j < je; j++)
            acc += wgt[j] * hw[(size_t)src[j] * H1 + f];
        h1[(size_t)i * H1 + f] = fmaxf(acc, 0.0f);
    }
    __threadfence();
    grid.sync();

    // ---- phase H: gemm23  t2 = h1@W2, t3 = h1@W3 ----
    for (int tile = bid; tile < N_NODES / 16; tile += nbg) {
        int i0 = tile * 16;
        __syncthreads();
        const float4* hsrc = (const float4*)(h1 + (size_t)i0 * H1);
        float4* hd = (float4*)smem;
#pragma unroll
        for (int j = 0; j < 2; j++) hd[tid + j * 256] = hsrc[tid + j * 256];
        __syncthreads();
        int f = tid & 63, sel = (tid >> 6) & 1, half = tid >> 7;  // wave-uniform sel
        const float* W = sel ? W3 : W2;
        const float* hrow = smem + (half * 8) * H1;
        float acc[8] = {0, 0, 0, 0, 0, 0, 0, 0};
        for (int k = 0; k < H1; k += 4) {
            float w0 = W[(k + 0) * H2 + f];
            float w1 = W[(k + 1) * H2 + f];
            float w2 = W[(k + 2) * H2 + f];
            float w3 = W[(k + 3) * H2 + f];
#pragma unroll
            for (int r = 0; r < 8; r++) {
                float4 hv = *(const float4*)&hrow[r * H1 + k];
                acc[r] += hv.x * w0 + hv.y * w1 + hv.z * w2 + hv.w * w3;
            }
        }
        float* o = sel ? t3 : t2;
#pragma unroll
        for (int r = 0; r < 8; r++)
            o[(size_t)(i0 + half * 8 + r) * H2 + f] = acc[r];
    }
    __threadfence();
    grid.sync();

    // ---- phase I: agg2  mu/logvar ----
    for (int ch = bid; ch < N_NODES / 2; ch += nbg) {
        int i = ch * 2 + (tid >> 7);
        int f = tid & 63, sel = (tid >> 6) & 1;
        const float* tin = sel ? t3 : t2;
        float acc = sel ? b3[f] : b2[f];
        int jb = ptr[i], je = ptr[i + 1];
        for (int j = jb; j < je; j++)
            acc += wgt[j] * tin[(size_t)src[j] * H2 + f];
        float* o = sel ? lv : mu;
        o[(size_t)i * H2 + f] = acc;
    }
}

// ---------------------------------------------------------------- adj = z z^T
//
// MFMA, 3-way exact bf16 split (z = h+m+l), 6 cross-term MFMAs, 128B-row XOR
// swizzle (round-2, verified).
// ROUND-4 change: FULL grid, and each block stores ONLY the transposed
// ("mirror") pattern: block (by,bx) computes D = Z_row Z_col^T and writes
// tile (bx,by) as float4 (lane's 4 acc regs = 4 consecutive columns of the
// transposed tile -> adj[cg][r0..r0+3], 16B aligned). By symmetry that IS the
// correct value, every tile is written exactly once, and ALL stores are
// dwordx4 (was: 4/5 scalar). Guards are all-or-nothing since r0 and N_NODES
// are both multiples of 4.
__global__ __launch_bounds__(256, 1) void k_adj(const float* __restrict__ z,
                                                float* __restrict__ adj) {
    __shared__ __align__(16) unsigned short PAs[128 * 64];
    __shared__ __align__(16) unsigned short PBs[128 * 64];
    __shared__ __align__(16) unsigned short PLs[128 * 64];
    int tid = threadIdx.x;
    int rowBase = blockIdx.y * 128, colBase = blockIdx.x * 128;

    int lane = tid & 63;
    int wv   = tid >> 6;
    int wr = (wv >> 1) * 64;               // wave's output quadrant
    int wc = (wv & 1) * 64;
    int lrow = lane & 15;
    int lk   = lane >> 4;                  // k-chunk (8 bf16) within 32-k stage

    int sr   = tid & 127;
    int isB  = tid >> 7;
    int gbase = (isB ? colBase : rowBase) + sr;
    bool ok = gbase < N_NODES;
    const float* srcp = z + (size_t)gbase * 64;
    unsigned short* PH = isB ? PBs : PAs;
    int lslotBase = isB ? 4 : 0;           // Al in slots 0-3 of PL, Bl in 4-7
    int rb7 = sr & 7;

    auto stage = [&](int s) {
#pragma unroll
        for (int g = 0; g < 4; g++) {      // 4 chunks of 8 k per 32-k stage
            float v[8];
            if (ok) {
                float4 a = *(const float4*)(srcp + s * 32 + g * 8);
                float4 b = *(const float4*)(srcp + s * 32 + g * 8 + 4);
                v[0] = a.x; v[1] = a.y; v[2] = a.z; v[3] = a.w;
                v[4] = b.x; v[5] = b.y; v[6] = b.z; v[7] = b.w;
            } else {
#pragma unroll
                for (int q = 0; q < 8; q++) v[q] = 0.0f;
            }
            u16v8 hv, mv, lv8;
#pragma unroll
            for (int q = 0; q < 8; q++) {
                float xv = v[q];
                unsigned hu = __float_as_uint(xv) & 0xffff0000u;       // h = trunc bf16
                float r1 = xv - __uint_as_float(hu);
                unsigned mu2 = __float_as_uint(r1) & 0xffff0000u;      // m
                float r2 = r1 - __uint_as_float(mu2);
                unsigned lu = __float_as_uint(r2) & 0xffff0000u;       // l
                hv[q]  = (unsigned short)(hu >> 16);
                mv[q]  = (unsigned short)(mu2 >> 16);
                lv8[q] = (unsigned short)(lu >> 16);
            }
            int base = sr * 64;
            *reinterpret_cast<u16v8*>(PH  + base + ((g              ^ rb7) * 8)) = hv;
            *reinterpret_cast<u16v8*>(PH  + base + (((4 + g)        ^ rb7) * 8)) = mv;
            *reinterpret_cast<u16v8*>(PLs + base + (((lslotBase + g) ^ rb7) * 8)) = lv8;
        }
    };

    f32v4 acc[4][4];
#pragma unroll
    for (int i = 0; i < 4; i++)
#pragma unroll
        for (int j = 0; j < 4; j++) acc[i][j] = (f32v4)0.0f;

    s16v8 a0[4], a1[4], a2[4], b0[4], b1[4], b2[4];

#define LOADFRAGS()                                                        \
    {                                                                      \
        _Pragma("unroll")                                                  \
        for (int fq = 0; fq < 4; fq++) {                                   \
            int ra = wr + fq * 16 + lrow;                                  \
            int r7 = ra & 7;                                               \
            int ia = ra * 64;                                              \
            a0[fq] = *reinterpret_cast<const s16v8*>(&PAs[ia + ((lk       ^ r7) * 8)]); \
            a1[fq] = *reinterpret_cast<const s16v8*>(&PAs[ia + (((4 + lk) ^ r7) * 8)]); \
            a2[fq] = *reinterpret_cast<const s16v8*>(&PLs[ia + ((lk       ^ r7) * 8)]); \
            int rb = wc + fq * 16 + lrow;                                  \
            int q7 = rb & 7;                                               \
            int ib = rb * 64;                                              \
            b0[fq] = *reinterpret_cast<const s16v8*>(&PBs[ib + ((lk       ^ q7) * 8)]); \
            b1[fq] = *reinterpret_cast<const s16v8*>(&PBs[ib + (((4 + lk) ^ q7) * 8)]); \
            b2[fq] = *reinterpret_cast<const s16v8*>(&PLs[ib + (((4 + lk) ^ q7) * 8)]); \
        }                                                                  \
    }

#define MFMAS()                                                            \
    {                                                                      \
        _Pragma("unroll")                                                  \
        for (int i = 0; i < 4; i++) {                                      \
            _Pragma("unroll")                                              \
            for (int j = 0; j < 4; j++) {                                  \
                f32v4 c = acc[i][j];                                       \
                c = __builtin_amdgcn_mfma_f32_16x16x32_bf16(a0[i], b0[j], c, 0, 0, 0); \
                c = __builtin_amdgcn_mfma_f32_16x16x32_bf16(a0[i], b1[j], c, 0, 0, 0); \
                c = __builtin_amdgcn_mfma_f32_16x16x32_bf16(a1[i], b0[j], c, 0, 0, 0); \
                c = __builtin_amdgcn_mfma_f32_16x16x32_bf16(a0[i], b2[j], c, 0, 0, 0); \
                c = __builtin_amdgcn_mfma_f32_16x16x32_bf16(a2[i], b0[j], c, 0, 0, 0); \
                c = __builtin_amdgcn_mfma_f32_16x16x32_bf16(a1[i], b1[j], c, 0, 0, 0); \
                acc[i][j] = c;                                             \
            }                                                              \
        }                                                                  \
    }

    stage(0);
    __syncthreads();
    LOADFRAGS();                // k-stage 0 frags -> regs
    __syncthreads();            // everyone done reading stage-0 LDS
    stage(1);                   // global loads overlap with MFMAs below
    MFMAS();                    // k 0..31
    __syncthreads();            // stage-1 writes visible
    LOADFRAGS();                // k-stage 1 frags
    MFMAS();                    // k 32..63

#undef LOADFRAGS
#undef MFMAS

    // transposed-tile store: all dwordx4.  acc[i][j][v] = D[wr+i*16+lk*4+v][wc+j*16+lrow]
    // = adj[rowBase+...][colBase+...] = adj[colBase+...][rowBase+...] (symmetry)
#pragma unroll
    for (int i = 0; i < 4; i++) {
        int r0 = rowBase + wr + i * 16 + lk * 4;       // column group (transposed tile)
        if (r0 < N_NODES) {                            // r0%4==0, N%4==0 -> all-or-nothing
#pragma unroll
            for (int j = 0; j < 4; j++) {
                int cg = colBase + wc + j * 16 + lrow; // row (transposed tile)
                if (cg < N_NODES)
                    *(float4*)&adj[(size_t)cg * N_NODES + r0] =
                        make_float4(acc[i][j][0], acc[i][j][1], acc[i][j][2], acc[i][j][3]);
            }
        }
    }
}

// ---------------------------------------------------------------- launch

extern "C" void kernel_launch(void* const* d_in, const int* in_sizes, int n_in,
                              void* d_out, int out_size, void* d_ws, size_t ws_size,
                              hipStream_t stream) {
    const float* x  = (const float*)d_in[0];
    const int*   ei = (const int*)d_in[1];      // harness passes ints as int32
    const float* w  = (const float*)d_in[2];
    const float* W1 = (const float*)d_in[3];
    const float* b1 = (const float*)d_in[4];
    const float* W2 = (const float*)d_in[5];
    const float* b2 = (const float*)d_in[6];
    const float* W3 = (const float*)d_in[7];
    const float* b3 = (const float*)d_in[8];

    float* out = (float*)d_out;
    float* adj = out;
    float* mu  = out + (size_t)N_NODES * N_NODES;
    float* lv  = mu + (size_t)N_NODES * H2;

    // Scratch in the tail of the adj region (offset 320 MB of the 400 MB adj
    // block). Dead before k_adj overwrites it; written before read every call.
    float* ws  = out + 80000000;
    float* deg = ws;                        // 10240 floats
    int*   cnt = (int*)(ws + 10240);        // 10240
    int*   ptr = (int*)(ws + 20480);        // 10240 (10001 used)
    int*   cur = (int*)(ws + 30720);        // 10240
    int*   src = (int*)(ws + 40960);        // 330240
    float* wgt = ws + 371200;               // 330240
    float* hw  = ws + 701440;               // 1,280,000
    float* h1  = ws + 1981440;              // 1,280,000
    float* t2  = ws + 3261440;              // 640,000
    float* t3  = ws + 3901440;              // 640,000
    int*   part = (int*)(ws + 4541440);     // 512

    // size the cooperative grid to actual co-residency (round-3 bug: 512
    // fixed blocks = 24% occupancy). Pure occupancy query — graph-capture safe.
    static int nbv = 0;
    if (nbv == 0) {
        int mb = 0;
        if (hipOccupancyMaxActiveBlocksPerMultiprocessor(&mb, k_mega, NT, 0) != hipSuccess
            || mb < 1) mb = 1;
        long nb = (long)mb * 256;           // 256 CUs on MI355X
        if (nb > 2048) nb = 2048;
        if (nb < 64) nb = 64;               // scan needs >=40 blocks
        nbv = (int)nb;
    }

    void* args[] = {
        (void*)&x,  (void*)&ei, (void*)&w,
        (void*)&W1, (void*)&b1, (void*)&W2, (void*)&b2, (void*)&W3, (void*)&b3,
        (void*)&deg, (void*)&cnt, (void*)&ptr, (void*)&cur, (void*)&part,
        (void*)&src, (void*)&wgt, (void*)&hw, (void*)&h1, (void*)&t2, (void*)&t3,
        (void*)&mu, (void*)&lv };
    hipLaunchCooperativeKernel((const void*)k_mega, dim3(nbv), dim3(NT), args, 0, stream);

    dim3 g((N_NODES + 127) / 128, (N_NODES + 127) / 128);
    hipLaunchKernelGGL(k_adj, g, dim3(256), 0, stream, mu, adj);
}

// Round 5
// 715.361 us; speedup vs baseline: 3.0151x; 3.0151x over previous
//
#include <hip/hip_runtime.h>

#define N_NODES 10000
#define F_IN    256
#define H1      128
#define H2      64
#define NEDGE   320000
#define M_TOT   (NEDGE + N_NODES)

typedef __attribute__((ext_vector_type(8))) short          s16v8;  // 8 bf16 (4 VGPRs)
typedef __attribute__((ext_vector_type(8))) unsigned short u16v8;
typedef __attribute__((ext_vector_type(4))) float          f32v4;

// ---------------------------------------------------------------- graph prep
// Discrete dispatches (round-2 structure). Cooperative fusion was tested in
// rounds 3-4 and is a dead end: grid.sync() cost scales ~linearly with block
// count (~100us+/sync at 512-2048 blocks; 98% occupancy, 1.6% VALUBusy).

__global__ void k_init(float* deg, int* cnt) {
    int i = blockIdx.x * blockDim.x + threadIdx.x;
    if (i < N_NODES) { deg[i] = 1.0f; cnt[i] = 1; }   // self-loop weight 1, count 1
}

__global__ void k_count(const int* __restrict__ ei, const float* __restrict__ w,
                        float* deg, int* cnt) {
    int e = blockIdx.x * blockDim.x + threadIdx.x;
    if (e < NEDGE) {
        int c = ei[NEDGE + e];                // col
        atomicAdd(&deg[c], w[e]);
        atomicAdd(&cnt[c], 1);
    }
}

// exclusive scan of cnt[0..N) -> ptr, one block of 1024 threads, 10 items each
__global__ void k_scan(const int* __restrict__ cnt, int* __restrict__ ptr,
                       int* __restrict__ cur) {
    __shared__ int part[1024];
    int t = threadIdx.x;
    int base = t * 10;
    int local[10];
    int s = 0;
#pragma unroll
    for (int j = 0; j < 10; j++) {
        int idx = base + j;
        int v = (idx < N_NODES) ? cnt[idx] : 0;
        local[j] = s;
        s += v;
    }
    part[t] = s;
    __syncthreads();
    for (int off = 1; off < 1024; off <<= 1) {
        int v = (t >= off) ? part[t - off] : 0;
        __syncthreads();
        part[t] += v;
        __syncthreads();
    }
    int excl = t ? part[t - 1] : 0;
#pragma unroll
    for (int j = 0; j < 10; j++) {
        int idx = base + j;
        if (idx < N_NODES) {
            int p = excl + local[j];
            ptr[idx] = p;
            cur[idx] = p;
        }
    }
    if (t == 1023) ptr[N_NODES] = part[1023];
}

// scatter edges (+self loops) into CSR-by-col; rsqrt folded in
__global__ void k_scatter(const int* __restrict__ ei, const float* __restrict__ w,
                          const float* __restrict__ deg, int* cur,
                          int* __restrict__ src, float* __restrict__ wgt) {
    int t = blockIdx.x * blockDim.x + threadIdx.x;
    if (t >= M_TOT) return;
    int r, c; float nw;
    if (t < NEDGE) {
        r = ei[t];
        c = ei[NEDGE + t];
        nw = rsqrtf(deg[r]) * w[t] * rsqrtf(deg[c]);   // same values as dis[r]*w*dis[c]
    } else {
        r = c = t - NEDGE;
        float d = rsqrtf(deg[r]);
        nw = d * d;
    }
    int pos = atomicAdd(&cur[c], 1);
    src[pos] = r;
    wgt[pos] = nw;
}

// ---------------------------------------------------------------- dense GEMM

// hw = x @ W1   [10000,256]x[256,128]; 8 rows/block, 128 threads (1 col each)
__global__ __launch_bounds__(128) void k_gemm1(const float* __restrict__ x,
                                               const float* __restrict__ W1,
                                               float* __restrict__ hw) {
    __shared__ float xs[8 * F_IN];
    int i0 = blockIdx.x * 8;
    int t = threadIdx.x;
    const float4* xsrc = (const float4*)(x + (size_t)i0 * F_IN);
    float4* xd = (float4*)xs;
#pragma unroll
    for (int j = 0; j < 4; j++) xd[t + j * 128] = xsrc[t + j * 128];
    __syncthreads();
    float acc[8] = {0, 0, 0, 0, 0, 0, 0, 0};
    for (int k = 0; k < F_IN; k += 4) {
        float w0 = W1[(k + 0) * H1 + t];
        float w1 = W1[(k + 1) * H1 + t];
        float w2 = W1[(k + 2) * H1 + t];
        float w3 = W1[(k + 3) * H1 + t];
#pragma unroll
        for (int r = 0; r < 8; r++) {
            float4 xv = *(const float4*)&xs[r * F_IN + k];   // wave-uniform broadcast
            acc[r] += xv.x * w0 + xv.y * w1 + xv.z * w2 + xv.w * w3;
        }
    }
#pragma unroll
    for (int r = 0; r < 8; r++) hw[(size_t)(i0 + r) * H1 + t] = acc[r];
}

// ------------------------------------------- fused agg1 + gemm23 (new, r5)
// Per node: h1_row = relu(segsum(norm*hw[row]) + b1) stays in LDS; then
// t2_row = h1_row @ W2, t3_row = h1_row @ W3 computed immediately.
// Saves one launch + the 10 MB h1 global round-trip. 2 nodes / 256-thr block.
__global__ __launch_bounds__(256) void k_agg1g23(const int* __restrict__ ptr,
                                                 const int* __restrict__ src,
                                                 const float* __restrict__ wgt,
                                                 const float* __restrict__ hw,
                                                 const float* __restrict__ b1,
                                                 const float* __restrict__ W2,
                                                 const float* __restrict__ W3,
                                                 float* __restrict__ t2,
                                                 float* __restrict__ t3) {
    __shared__ float h1s[2][H1];
    int tid = threadIdx.x;
    // phase 1: half-block per node, 128 feats each
    {
        int half = tid >> 7;
        int f = tid & 127;
        int i = blockIdx.x * 2 + half;
        int jb = ptr[i], je = ptr[i + 1];
        float acc = b1[f];
        for (int j = jb; j < je; j++)
            acc += wgt[j] * hw[(size_t)src[j] * H1 + f];
        h1s[half][f] = fmaxf(acc, 0.0f);
    }
    __syncthreads();
    // phase 2: wave wv -> {node wv>>1} x {W2 if !(wv&1) else W3}, 64 cols each
    {
        int f = tid & 63;
        int wv = tid >> 6;                 // wave-uniform
        int sel = wv & 1, nh = wv >> 1;
        const float* W = sel ? W3 : W2;
        const float* hr = h1s[nh];
        float s = 0.0f;
        for (int k = 0; k < H1; k += 4) {
            float4 hv = *(const float4*)&hr[k];              // wave-uniform broadcast
            s += hv.x * W[(k + 0) * H2 + f] + hv.y * W[(k + 1) * H2 + f]
               + hv.z * W[(k + 2) * H2 + f] + hv.w * W[(k + 3) * H2 + f];
        }
        int node = blockIdx.x * 2 + nh;
        float* o = sel ? t3 : t2;
        o[(size_t)node * H2 + f] = s;      // bias added in agg2
    }
}

// mu = segsum(norm * t2[row]) + b2 ; logvar = ... t3/b3.  wave0->mu, wave1->logvar
__global__ __launch_bounds__(128) void k_agg2(const int* __restrict__ ptr,
                                              const int* __restrict__ src,
                                              const float* __restrict__ wgt,
                                              const float* __restrict__ t2,
                                              const float* __restrict__ t3,
                                              const float* __restrict__ b2,
                                              const float* __restrict__ b3,
                                              float* __restrict__ mu,
                                              float* __restrict__ lv) {
    int i = blockIdx.x;
    int t = threadIdx.x;
    int f = t & 63;
    int sel = t >> 6;                      // wave-uniform
    const float* tin = sel ? t3 : t2;
    float acc = sel ? b3[f] : b2[f];
    int jb = ptr[i], je = ptr[i + 1];
    for (int j = jb; j < je; j++)
        acc += wgt[j] * tin[(size_t)src[j] * H2 + f];
    float* o = sel ? lv : mu;
    o[(size_t)i * H2 + f] = acc;
}

// ---------------------------------------------------------------- adj = z z^T
//
// MFMA, 3-way exact bf16 split (z = h+m+l), 6 cross-term MFMAs, 128B-row XOR
// swizzle (round-2, verified). v3 epilogue: FULL grid; each block stores ONLY
// the transposed tile — block (by,bx) computes D = Z_row Z_col^T and writes
// tile (bx,by) as float4 (lane's 4 acc regs = 4 consecutive columns of the
// transposed tile). By symmetry that IS the correct value, every tile written
// exactly once, ALL stores are dwordx4 (round-2 had 64 scalar stores/thread).
__global__ __launch_bounds__(256, 1) void k_adj(const float* __restrict__ z,
                                                float* __restrict__ adj) {
    __shared__ __align__(16) unsigned short PAs[128 * 64];
    __shared__ __align__(16) unsigned short PBs[128 * 64];
    __shared__ __align__(16) unsigned short PLs[128 * 64];
    int tid = threadIdx.x;
    int rowBase = blockIdx.y * 128, colBase = blockIdx.x * 128;

    int lane = tid & 63;
    int wv   = tid >> 6;
    int wr = (wv >> 1) * 64;               // wave's output quadrant
    int wc = (wv & 1) * 64;
    int lrow = lane & 15;
    int lk   = lane >> 4;                  // k-chunk (8 bf16) within 32-k stage

    int sr   = tid & 127;
    int isB  = tid >> 7;
    int gbase = (isB ? colBase : rowBase) + sr;
    bool ok = gbase < N_NODES;
    const float* srcp = z + (size_t)gbase * 64;
    unsigned short* PH = isB ? PBs : PAs;
    int lslotBase = isB ? 4 : 0;           // Al in slots 0-3 of PL, Bl in 4-7
    int rb7 = sr & 7;

    auto stage = [&](int s) {
#pragma unroll
        for (int g = 0; g < 4; g++) {      // 4 chunks of 8 k per 32-k stage
            float v[8];
            if (ok) {
                float4 a = *(const float4*)(srcp + s * 32 + g * 8);
                float4 b = *(const float4*)(srcp + s * 32 + g * 8 + 4);
                v[0] = a.x; v[1] = a.y; v[2] = a.z; v[3] = a.w;
                v[4] = b.x; v[5] = b.y; v[6] = b.z; v[7] = b.w;
            } else {
#pragma unroll
                for (int q = 0; q < 8; q++) v[q] = 0.0f;
            }
            u16v8 hv, mv, lv8;
#pragma unroll
            for (int q = 0; q < 8; q++) {
                float xv = v[q];
                unsigned hu = __float_as_uint(xv) & 0xffff0000u;       // h = trunc bf16
                float r1 = xv - __uint_as_float(hu);
                unsigned mu2 = __float_as_uint(r1) & 0xffff0000u;      // m
                float r2 = r1 - __uint_as_float(mu2);
                unsigned lu = __float_as_uint(r2) & 0xffff0000u;       // l
                hv[q]  = (unsigned short)(hu >> 16);
                mv[q]  = (unsigned short)(mu2 >> 16);
                lv8[q] = (unsigned short)(lu >> 16);
            }
            int base = sr * 64;
            *reinterpret_cast<u16v8*>(PH  + base + ((g              ^ rb7) * 8)) = hv;
            *reinterpret_cast<u16v8*>(PH  + base + (((4 + g)        ^ rb7) * 8)) = mv;
            *reinterpret_cast<u16v8*>(PLs + base + (((lslotBase + g) ^ rb7) * 8)) = lv8;
        }
    };

    f32v4 acc[4][4];
#pragma unroll
    for (int i = 0; i < 4; i++)
#pragma unroll
        for (int j = 0; j < 4; j++) acc[i][j] = (f32v4)0.0f;

    s16v8 a0[4], a1[4], a2[4], b0[4], b1[4], b2[4];

#define LOADFRAGS()                                                        \
    {                                                                      \
        _Pragma("unroll")                                                  \
        for (int fq = 0; fq < 4; fq++) {                                   \
            int ra = wr + fq * 16 + lrow;                                  \
            int r7 = ra & 7;                                               \
            int ia = ra * 64;                                              \
            a0[fq] = *reinterpret_cast<const s16v8*>(&PAs[ia + ((lk       ^ r7) * 8)]); \
            a1[fq] = *reinterpret_cast<const s16v8*>(&PAs[ia + (((4 + lk) ^ r7) * 8)]); \
            a2[fq] = *reinterpret_cast<const s16v8*>(&PLs[ia + ((lk       ^ r7) * 8)]); \
            int rb = wc + fq * 16 + lrow;                                  \
            int q7 = rb & 7;                                               \
            int ib = rb * 64;                                              \
            b0[fq] = *reinterpret_cast<const s16v8*>(&PBs[ib + ((lk       ^ q7) * 8)]); \
            b1[fq] = *reinterpret_cast<const s16v8*>(&PBs[ib + (((4 + lk) ^ q7) * 8)]); \
            b2[fq] = *reinterpret_cast<const s16v8*>(&PLs[ib + (((4 + lk) ^ q7) * 8)]); \
        }                                                                  \
    }

#define MFMAS()                                                            \
    {                                                                      \
        _Pragma("unroll")                                                  \
        for (int i = 0; i < 4; i++) {                                      \
            _Pragma("unroll")                                              \
            for (int j = 0; j < 4; j++) {                                  \
                f32v4 c = acc[i][j];                                       \
                c = __builtin_amdgcn_mfma_f32_16x16x32_bf16(a0[i], b0[j], c, 0, 0, 0); \
                c = __builtin_amdgcn_mfma_f32_16x16x32_bf16(a0[i], b1[j], c, 0, 0, 0); \
                c = __builtin_amdgcn_mfma_f32_16x16x32_bf16(a1[i], b0[j], c, 0, 0, 0); \
                c = __builtin_amdgcn_mfma_f32_16x16x32_bf16(a0[i], b2[j], c, 0, 0, 0); \
                c = __builtin_amdgcn_mfma_f32_16x16x32_bf16(a2[i], b0[j], c, 0, 0, 0); \
                c = __builtin_amdgcn_mfma_f32_16x16x32_bf16(a1[i], b1[j], c, 0, 0, 0); \
                acc[i][j] = c;                                             \
            }                                                              \
        }                                                                  \
    }

    stage(0);
    __syncthreads();
    LOADFRAGS();                // k-stage 0 frags -> regs
    __syncthreads();            // everyone done reading stage-0 LDS
    stage(1);                   // global loads overlap with MFMAs below
    MFMAS();                    // k 0..31
    __syncthreads();            // stage-1 writes visible
    LOADFRAGS();                // k-stage 1 frags
    MFMAS();                    // k 32..63

#undef LOADFRAGS
#undef MFMAS

    // transposed-tile store: all dwordx4.
    // acc[i][j][v] = D[wr+i*16+lk*4+v][wc+j*16+lrow] = adj[cg][r0+v] by symmetry.
#pragma unroll
    for (int i = 0; i < 4; i++) {
        int r0 = rowBase + wr + i * 16 + lk * 4;       // column group (transposed tile)
        if (r0 < N_NODES) {                            // r0%4==0, N%4==0 -> all-or-nothing
#pragma unroll
            for (int j = 0; j < 4; j++) {
                int cg = colBase + wc + j * 16 + lrow; // row (transposed tile)
                if (cg < N_NODES)
                    *(float4*)&adj[(size_t)cg * N_NODES + r0] =
                        make_float4(acc[i][j][0], acc[i][j][1], acc[i][j][2], acc[i][j][3]);
            }
        }
    }
}

// ---------------------------------------------------------------- launch

extern "C" void kernel_launch(void* const* d_in, const int* in_sizes, int n_in,
                              void* d_out, int out_size, void* d_ws, size_t ws_size,
                              hipStream_t stream) {
    const float* x  = (const float*)d_in[0];
    const int*   ei = (const int*)d_in[1];      // harness passes ints as int32
    const float* w  = (const float*)d_in[2];
    const float* W1 = (const float*)d_in[3];
    const float* b1 = (const float*)d_in[4];
    const float* W2 = (const float*)d_in[5];
    const float* b2 = (const float*)d_in[6];
    const float* W3 = (const float*)d_in[7];
    const float* b3 = (const float*)d_in[8];

    float* out = (float*)d_out;
    float* adj = out;
    float* mu  = out + (size_t)N_NODES * N_NODES;
    float* lv  = mu + (size_t)N_NODES * H2;

    // Scratch in the tail of the adj region (offset 320 MB of the 400 MB adj
    // block). Dead before k_adj overwrites it; written before read every call.
    float* ws  = out + 80000000;
    float* deg = ws;                        // 10240 floats
    int*   cnt = (int*)(ws + 10240);        // 10240
    int*   ptr = (int*)(ws + 20480);        // 10240 (10001 used)
    int*   cur = (int*)(ws + 30720);        // 10240
    int*   src = (int*)(ws + 40960);        // 330240
    float* wgt = ws + 371200;               // 330240
    float* hw  = ws + 701440;               // 1,280,000
    float* t2  = ws + 3261440;              // 640,000
    float* t3  = ws + 3901440;              // 640,000

    hipLaunchKernelGGL(k_init,    dim3((N_NODES + 255) / 256), dim3(256), 0, stream, deg, cnt);
    hipLaunchKernelGGL(k_count,   dim3((NEDGE + 255) / 256),   dim3(256), 0, stream, ei, w, deg, cnt);
    hipLaunchKernelGGL(k_scan,    dim3(1), dim3(1024), 0, stream, cnt, ptr, cur);
    hipLaunchKernelGGL(k_scatter, dim3((M_TOT + 255) / 256),   dim3(256), 0, stream, ei, w, deg, cur, src, wgt);
    hipLaunchKernelGGL(k_gemm1,   dim3(N_NODES / 8),  dim3(128), 0, stream, x, W1, hw);
    hipLaunchKernelGGL(k_agg1g23, dim3(N_NODES / 2),  dim3(256), 0, stream, ptr, src, wgt, hw, b1, W2, W3, t2, t3);
    hipLaunchKernelGGL(k_agg2,    dim3(N_NODES),      dim3(128), 0, stream, ptr, src, wgt, t2, t3, b2, b3, mu, lv);

    dim3 g((N_NODES + 127) / 128, (N_NODES + 127) / 128);
    hipLaunchKernelGGL(k_adj, g, dim3(256), 0, stream, mu, adj);
}

// Round 6
// 661.536 us; speedup vs baseline: 3.2604x; 1.0814x over previous
//
#include <hip/hip_runtime.h>

#define N_NODES 10000
#define F_IN    256
#define H1      128
#define H2      64
#define NEDGE   320000
#define M_TOT   (NEDGE + N_NODES)
#define BCAP    128            // bucket capacity per node (P(deg>=128) ~ 1e-40)

typedef __attribute__((ext_vector_type(8))) short          s16v8;  // 8 bf16 (4 VGPRs)
typedef __attribute__((ext_vector_type(8))) unsigned short u16v8;
typedef __attribute__((ext_vector_type(4))) float          f32v4;

// ---------------------------------------------------------------- prep
// Bucket-CSR: fixed 128-slot buckets per node + atomic slot counters.
// Removes the serial one-block scan and two launches vs the CSR chain.

__global__ void k_zero(float* deg, int* cur) {
    int i = blockIdx.x * blockDim.x + threadIdx.x;
    if (i < N_NODES) { deg[i] = 0.0f; cur[i] = 0; }
}

// blocks [0,625): gemm1 (hw = x@W1, 16 rows/block); blocks [625,1875): deg count
__global__ __launch_bounds__(256) void k_cg1(const float* __restrict__ x,
                                             const float* __restrict__ W1,
                                             float* __restrict__ hw,
                                             const int* __restrict__ ei,
                                             const float* __restrict__ w,
                                             float* deg) {
    __shared__ float xs[16 * F_IN];
    int bid = blockIdx.x;
    int tid = threadIdx.x;
    if (bid < 625) {
        int i0 = bid * 16;
        const float4* xsrc = (const float4*)(x + (size_t)i0 * F_IN);
        float4* xd = (float4*)xs;
#pragma unroll
        for (int j = 0; j < 4; j++) xd[tid + j * 256] = xsrc[tid + j * 256];
        __syncthreads();
        int col = tid & 127, half = tid >> 7;
        const float* xrow = xs + (half * 8) * F_IN;
        float acc[8] = {0, 0, 0, 0, 0, 0, 0, 0};
        for (int k = 0; k < F_IN; k += 4) {
            float w0 = W1[(k + 0) * H1 + col];
            float w1 = W1[(k + 1) * H1 + col];
            float w2 = W1[(k + 2) * H1 + col];
            float w3 = W1[(k + 3) * H1 + col];
#pragma unroll
            for (int r = 0; r < 8; r++) {
                float4 xv = *(const float4*)&xrow[r * F_IN + k];   // wave-uniform bcast
                acc[r] += xv.x * w0 + xv.y * w1 + xv.z * w2 + xv.w * w3;
            }
        }
#pragma unroll
        for (int r = 0; r < 8; r++)
            hw[(size_t)(i0 + half * 8 + r) * H1 + col] = acc[r];
    } else {
        int e = (bid - 625) * 256 + tid;
        if (e < NEDGE) atomicAdd(&deg[ei[NEDGE + e]], w[e]);
    }
}

// scatter edges (+self loops) into buckets; norm = rsqrt(1+degsum) each side
// (identical values to the CSR chain's dis[r]*w*dis[c] with self-loop weight 1)
__global__ void k_scatb(const int* __restrict__ ei, const float* __restrict__ w,
                        const float* __restrict__ deg, int* cur,
                        int* __restrict__ bsrc, float* __restrict__ bwgt) {
    int t = blockIdx.x * blockDim.x + threadIdx.x;
    if (t >= M_TOT) return;
    int r, c; float nw;
    if (t < NEDGE) {
        r = ei[t];
        c = ei[NEDGE + t];
        nw = rsqrtf(1.0f + deg[r]) * w[t] * rsqrtf(1.0f + deg[c]);
    } else {
        r = c = t - NEDGE;
        float d = rsqrtf(1.0f + deg[r]);
        nw = d * d;
    }
    int pos = atomicAdd(&cur[c], 1);
    bsrc[(c << 7) + pos] = r;
    bwgt[(c << 7) + pos] = nw;
}

// ------------------------------------------- fused agg1 + gemm23
// h1 row stays in LDS; t2/t3 rows produced immediately. 2 nodes/256-thr block.
__global__ __launch_bounds__(256) void k_agg1g23(const int* __restrict__ cur,
                                                 const int* __restrict__ bsrc,
                                                 const float* __restrict__ bwgt,
                                                 const float* __restrict__ hw,
                                                 const float* __restrict__ b1,
                                                 const float* __restrict__ W2,
                                                 const float* __restrict__ W3,
                                                 float* __restrict__ t2,
                                                 float* __restrict__ t3) {
    __shared__ float h1s[2][H1];
    int tid = threadIdx.x;
    {
        int half = tid >> 7;
        int f = tid & 127;
        int i = blockIdx.x * 2 + half;
        int n = cur[i];
        const int*   bs = bsrc + ((size_t)i << 7);
        const float* bw = bwgt + ((size_t)i << 7);
        float acc = b1[f];
        for (int j = 0; j < n; j++)
            acc += bw[j] * hw[(size_t)bs[j] * H1 + f];
        h1s[half][f] = fmaxf(acc, 0.0f);
    }
    __syncthreads();
    {
        int f = tid & 63;
        int wv = tid >> 6;                 // wave-uniform
        int sel = wv & 1, nh = wv >> 1;
        const float* W = sel ? W3 : W2;
        const float* hr = h1s[nh];
        float s = 0.0f;
        for (int k = 0; k < H1; k += 4) {
            float4 hv = *(const float4*)&hr[k];              // wave-uniform broadcast
            s += hv.x * W[(k + 0) * H2 + f] + hv.y * W[(k + 1) * H2 + f]
               + hv.z * W[(k + 2) * H2 + f] + hv.w * W[(k + 3) * H2 + f];
        }
        int node = blockIdx.x * 2 + nh;
        float* o = sel ? t3 : t2;
        o[(size_t)node * H2 + f] = s;      // bias added in agg2
    }
}

// mu = segsum(norm * t2[row]) + b2 ; logvar likewise. wave0->mu, wave1->logvar
__global__ __launch_bounds__(128) void k_agg2(const int* __restrict__ cur,
                                              const int* __restrict__ bsrc,
                                              const float* __restrict__ bwgt,
                                              const float* __restrict__ t2,
                                              const float* __restrict__ t3,
                                              const float* __restrict__ b2,
                                              const float* __restrict__ b3,
                                              float* __restrict__ mu,
                                              float* __restrict__ lv) {
    int i = blockIdx.x;
    int t = threadIdx.x;
    int f = t & 63;
    int sel = t >> 6;                      // wave-uniform
    const float* tin = sel ? t3 : t2;
    float acc = sel ? b3[f] : b2[f];
    int n = cur[i];
    const int*   bs = bsrc + ((size_t)i << 7);
    const float* bw = bwgt + ((size_t)i << 7);
    for (int j = 0; j < n; j++)
        acc += bw[j] * tin[(size_t)bs[j] * H2 + f];
    float* o = sel ? lv : mu;
    o[(size_t)i * H2 + f] = acc;
}

// ---------------------------------------------------------------- adj = z z^T
//
// MFMA, 3-way exact bf16 split (z = h+m+l), 6 cross-term MFMAs, 128B-row XOR
// swizzle (verified r2). ROUND-6: revert epilogue to the DIRECT scalar store
// pattern (R1 — empirically best total): per instruction a wave writes 4 rows
// x 64B contiguous, vs the transposed-float4 pattern's 16 scattered rows x
// 64B (R5, +38us). Full grid, every block writes its own tile exactly once.
// launch_bounds(256,2): 2 blocks/CU co-residency (LDS 48KB -> 2 fit; VGPR
// capped 256) so staging of block n+1 overlaps MFMA/stores of block n.
__global__ __launch_bounds__(256, 2) void k_adj(const float* __restrict__ z,
                                                float* __restrict__ adj) {
    __shared__ __align__(16) unsigned short PAs[128 * 64];
    __shared__ __align__(16) unsigned short PBs[128 * 64];
    __shared__ __align__(16) unsigned short PLs[128 * 64];
    int tid = threadIdx.x;
    int rowBase = blockIdx.y * 128, colBase = blockIdx.x * 128;

    int lane = tid & 63;
    int wv   = tid >> 6;
    int wr = (wv >> 1) * 64;               // wave's output quadrant
    int wc = (wv & 1) * 64;
    int lrow = lane & 15;
    int lk   = lane >> 4;                  // k-chunk (8 bf16) within 32-k stage

    int sr   = tid & 127;
    int isB  = tid >> 7;
    int gbase = (isB ? colBase : rowBase) + sr;
    bool ok = gbase < N_NODES;
    const float* srcp = z + (size_t)gbase * 64;
    unsigned short* PH = isB ? PBs : PAs;
    int lslotBase = isB ? 4 : 0;           // Al in slots 0-3 of PL, Bl in 4-7
    int rb7 = sr & 7;

    auto stage = [&](int s) {
#pragma unroll
        for (int g = 0; g < 4; g++) {      // 4 chunks of 8 k per 32-k stage
            float v[8];
            if (ok) {
                float4 a = *(const float4*)(srcp + s * 32 + g * 8);
                float4 b = *(const float4*)(srcp + s * 32 + g * 8 + 4);
                v[0] = a.x; v[1] = a.y; v[2] = a.z; v[3] = a.w;
                v[4] = b.x; v[5] = b.y; v[6] = b.z; v[7] = b.w;
            } else {
#pragma unroll
                for (int q = 0; q < 8; q++) v[q] = 0.0f;
            }
            u16v8 hv, mv, lv8;
#pragma unroll
            for (int q = 0; q < 8; q++) {
                float xv = v[q];
                unsigned hu = __float_as_uint(xv) & 0xffff0000u;       // h = trunc bf16
                float r1 = xv - __uint_as_float(hu);
                unsigned mu2 = __float_as_uint(r1) & 0xffff0000u;      // m
                float r2 = r1 - __uint_as_float(mu2);
                unsigned lu = __float_as_uint(r2) & 0xffff0000u;       // l
                hv[q]  = (unsigned short)(hu >> 16);
                mv[q]  = (unsigned short)(mu2 >> 16);
                lv8[q] = (unsigned short)(lu >> 16);
            }
            int base = sr * 64;
            *reinterpret_cast<u16v8*>(PH  + base + ((g              ^ rb7) * 8)) = hv;
            *reinterpret_cast<u16v8*>(PH  + base + (((4 + g)        ^ rb7) * 8)) = mv;
            *reinterpret_cast<u16v8*>(PLs + base + (((lslotBase + g) ^ rb7) * 8)) = lv8;
        }
    };

    f32v4 acc[4][4];
#pragma unroll
    for (int i = 0; i < 4; i++)
#pragma unroll
        for (int j = 0; j < 4; j++) acc[i][j] = (f32v4)0.0f;

    s16v8 a0[4], a1[4], a2[4], b0[4], b1[4], b2[4];

#define LOADFRAGS()                                                        \
    {                                                                      \
        _Pragma("unroll")                                                  \
        for (int fq = 0; fq < 4; fq++) {                                   \
            int ra = wr + fq * 16 + lrow;                                  \
            int r7 = ra & 7;                                               \
            int ia = ra * 64;                                              \
            a0[fq] = *reinterpret_cast<const s16v8*>(&PAs[ia + ((lk       ^ r7) * 8)]); \
            a1[fq] = *reinterpret_cast<const s16v8*>(&PAs[ia + (((4 + lk) ^ r7) * 8)]); \
            a2[fq] = *reinterpret_cast<const s16v8*>(&PLs[ia + ((lk       ^ r7) * 8)]); \
            int rb = wc + fq * 16 + lrow;                                  \
            int q7 = rb & 7;                                               \
            int ib = rb * 64;                                              \
            b0[fq] = *reinterpret_cast<const s16v8*>(&PBs[ib + ((lk       ^ q7) * 8)]); \
            b1[fq] = *reinterpret_cast<const s16v8*>(&PBs[ib + (((4 + lk) ^ q7) * 8)]); \
            b2[fq] = *reinterpret_cast<const s16v8*>(&PLs[ib + (((4 + lk) ^ q7) * 8)]); \
        }                                                                  \
    }

#define MFMAS()                                                            \
    {                                                                      \
        _Pragma("unroll")                                                  \
        for (int i = 0; i < 4; i++) {                                      \
            _Pragma("unroll")                                              \
            for (int j = 0; j < 4; j++) {                                  \
                f32v4 c = acc[i][j];                                       \
                c = __builtin_amdgcn_mfma_f32_16x16x32_bf16(a0[i], b0[j], c, 0, 0, 0); \
                c = __builtin_amdgcn_mfma_f32_16x16x32_bf16(a0[i], b1[j], c, 0, 0, 0); \
                c = __builtin_amdgcn_mfma_f32_16x16x32_bf16(a1[i], b0[j], c, 0, 0, 0); \
                c = __builtin_amdgcn_mfma_f32_16x16x32_bf16(a0[i], b2[j], c, 0, 0, 0); \
                c = __builtin_amdgcn_mfma_f32_16x16x32_bf16(a2[i], b0[j], c, 0, 0, 0); \
                c = __builtin_amdgcn_mfma_f32_16x16x32_bf16(a1[i], b1[j], c, 0, 0, 0); \
                acc[i][j] = c;                                             \
            }                                                              \
        }                                                                  \
    }

    stage(0);
    __syncthreads();
    LOADFRAGS();                // k-stage 0 frags -> regs
    __syncthreads();            // everyone done reading stage-0 LDS
    stage(1);                   // global loads overlap with MFMAs below
    MFMAS();                    // k 0..31
    __syncthreads();            // stage-1 writes visible
    LOADFRAGS();                // k-stage 1 frags
    MFMAS();                    // k 32..63

#undef LOADFRAGS
#undef MFMAS

    // direct-tile store (R1 pattern): per (i,j,v) instruction a wave writes
    // 4 rows x 64B contiguous segments.
#pragma unroll
    for (int i = 0; i < 4; i++) {
        int r0 = rowBase + wr + i * 16 + lk * 4;
#pragma unroll
        for (int j = 0; j < 4; j++) {
            int cg = colBase + wc + j * 16 + lrow;
            if (cg < N_NODES) {
#pragma unroll
                for (int v = 0; v < 4; v++) {
                    int rg = r0 + v;
                    if (rg < N_NODES)
                        adj[(size_t)rg * N_NODES + cg] = acc[i][j][v];
                }
            }
        }
    }
}

// ---------------------------------------------------------------- launch

extern "C" void kernel_launch(void* const* d_in, const int* in_sizes, int n_in,
                              void* d_out, int out_size, void* d_ws, size_t ws_size,
                              hipStream_t stream) {
    const float* x  = (const float*)d_in[0];
    const int*   ei = (const int*)d_in[1];      // harness passes ints as int32
    const float* w  = (const float*)d_in[2];
    const float* W1 = (const float*)d_in[3];
    const float* b1 = (const float*)d_in[4];
    const float* W2 = (const float*)d_in[5];
    const float* b2 = (const float*)d_in[6];
    const float* W3 = (const float*)d_in[7];
    const float* b3 = (const float*)d_in[8];

    float* out = (float*)d_out;
    float* adj = out;
    float* mu  = out + (size_t)N_NODES * N_NODES;
    float* lv  = mu + (size_t)N_NODES * H2;

    // Scratch in the tail of the adj region (offset 320 MB of the 400 MB adj
    // block). Dead before k_adj overwrites it; written before read every call.
    float* ws   = out + 80000000;
    float* deg  = ws;                        // 10240 floats
    int*   cur  = (int*)(ws + 10240);        // 10240
    int*   bsrc = (int*)(ws + 20480);        // 1,280,000 (10000 x 128)
    float* bwgt = ws + 1300480;              // 1,280,000
    float* hw   = ws + 2580480;              // 1,280,000
    float* t2   = ws + 3860480;              // 640,000
    float* t3   = ws + 4500480;              // 640,000 (ends ws+5,140,480)

    hipLaunchKernelGGL(k_zero,    dim3((N_NODES + 255) / 256), dim3(256), 0, stream, deg, cur);
    hipLaunchKernelGGL(k_cg1,     dim3(625 + (NEDGE + 255) / 256), dim3(256), 0, stream,
                       x, W1, hw, ei, w, deg);
    hipLaunchKernelGGL(k_scatb,   dim3((M_TOT + 255) / 256), dim3(256), 0, stream,
                       ei, w, deg, cur, bsrc, bwgt);
    hipLaunchKernelGGL(k_agg1g23, dim3(N_NODES / 2), dim3(256), 0, stream,
                       cur, bsrc, bwgt, hw, b1, W2, W3, t2, t3);
    hipLaunchKernelGGL(k_agg2,    dim3(N_NODES), dim3(128), 0, stream,
                       cur, bsrc, bwgt, t2, t3, b2, b3, mu, lv);

    dim3 g((N_NODES + 127) / 128, (N_NODES + 127) / 128);
    hipLaunchKernelGGL(k_adj, g, dim3(256), 0, stream, mu, adj);
}